// Round 1
// baseline (522.385 us; speedup 1.0000x reference)
//
#include <hip/hip_runtime.h>
#include <math.h>

#define N_QDIM 256
#define N_EDIM 512
#define N_HEADS 8
#define N_HDIM 64
#define N_TOK 10
#define NJ 80   // N_HEADS * N_TOK

// ---------------------------------------------------------------------------
// Precompute: keys_raw = tanh(embed)  (10x64)
//             K = keys_raw @ Wk.T     (10x512)
//             Ws[qd][j] = (1/8) * sum_d Wq[h*64+d][qd] * K[t][h*64+d]
//                         where j = h*10 + t    -> (256x80)
// 80 blocks x 256 threads; phases 1-2 are redundantly computed per block
// (cheap), phase 3 computes exactly one Ws element per thread.
// ---------------------------------------------------------------------------
__global__ __launch_bounds__(256) void precompute_kernel(
    const float* __restrict__ embed, const float* __restrict__ Wq,
    const float* __restrict__ Wk, float* __restrict__ Ws,
    float* __restrict__ keysOut)
{
    __shared__ float skeys[N_TOK * N_HDIM];   // 640
    __shared__ float sK[N_TOK * N_EDIM];      // 5120
    const int tid = threadIdx.x;

    for (int i = tid; i < N_TOK * N_HDIM; i += 256) {
        float v = tanhf(embed[i]);
        skeys[i] = v;
        if (blockIdx.x == 0) keysOut[i] = v;
    }
    __syncthreads();

    for (int i = tid; i < N_TOK * N_EDIM; i += 256) {
        int t = i >> 9;          // / 512
        int e = i & 511;
        float s = 0.f;
        #pragma unroll
        for (int d = 0; d < N_HDIM; d++)
            s += skeys[t * N_HDIM + d] * Wk[e * N_HDIM + d];
        sK[i] = s;
    }
    __syncthreads();

    int v = blockIdx.x * 256 + tid;   // 0..20479 == 256*80
    int qd = v / NJ;
    int j  = v - qd * NJ;
    int h  = j / N_TOK;
    int t  = j - h * N_TOK;
    float s = 0.f;
    #pragma unroll
    for (int d = 0; d < N_HDIM; d++)
        s += Wq[(h * N_HDIM + d) * N_QDIM + qd] * sK[t * N_EDIM + h * N_HDIM + d];
    Ws[qd * NJ + j] = s * 0.125f;     // fold 1/sqrt(64)
}

// ---------------------------------------------------------------------------
// Main: scores (Nx80) = inputs (Nx256) @ Ws (256x80); write attn;
//       out (Nx512)   = per-head scores (Nx10) @ keys_raw (10x64)
// BM=128 rows/block, BK=32, 256 threads as 16(tr: rows) x 16(tc: cols),
// thread tile 8 rows x 5 cols.
// ---------------------------------------------------------------------------
__global__ __launch_bounds__(256) void main_kernel(
    const float* __restrict__ inputs, const float* __restrict__ Ws,
    const float* __restrict__ keys, float* __restrict__ outStyle,
    float* __restrict__ outAttn, int N)
{
    __shared__ float smem[128 * 81];      // 41472 B; GEMM phase uses 6784 floats
    float* sA = smem;                     // [32][132] (pad 128->132 keeps 16B align)
    float* sB = smem + 32 * 132;          // [32][80]

    const int tid = threadIdx.x;
    const int tc = tid & 15;
    const int tr = tid >> 4;
    const int n0 = blockIdx.x * 128;
    const float* A = inputs + (size_t)n0 * N_QDIM;

    float acc[8][5];
    #pragma unroll
    for (int i = 0; i < 8; i++)
        #pragma unroll
        for (int j = 0; j < 5; j++) acc[i][j] = 0.f;

    for (int kb = 0; kb < N_QDIM; kb += 32) {
        __syncthreads();
        // stage A tile (128 rows x 32 k), transposed into sA[k][row]
        #pragma unroll
        for (int it = 0; it < 4; it++) {
            int flat = it * 256 + tid;          // 0..1023 float4 chunks
            int row = flat >> 3;
            int ch  = flat & 7;
            float4 v = *(const float4*)(A + row * N_QDIM + kb + ch * 4);
            int k = ch * 4;
            sA[(k + 0) * 132 + row] = v.x;
            sA[(k + 1) * 132 + row] = v.y;
            sA[(k + 2) * 132 + row] = v.z;
            sA[(k + 3) * 132 + row] = v.w;
        }
        // stage B tile (32 k x 80 j) -- contiguous copy
        #pragma unroll
        for (int it = 0; it < 3; it++) {
            int f = it * 256 + tid;             // 640 float4 total
            if (f < 640)
                *(float4*)(sB + f * 4) = *(const float4*)(Ws + kb * NJ + f * 4);
        }
        __syncthreads();
        #pragma unroll
        for (int k = 0; k < 32; k++) {
            float4 a0 = *(const float4*)(sA + k * 132 + tr * 8);
            float4 a1 = *(const float4*)(sA + k * 132 + tr * 8 + 4);
            float b[5];
            #pragma unroll
            for (int j = 0; j < 5; j++) b[j] = sB[k * NJ + tc * 5 + j];
            float a[8] = {a0.x, a0.y, a0.z, a0.w, a1.x, a1.y, a1.z, a1.w};
            #pragma unroll
            for (int i = 0; i < 8; i++)
                #pragma unroll
                for (int j = 0; j < 5; j++)
                    acc[i][j] += a[i] * b[j];
        }
    }

    __syncthreads();
    // stage scores into LDS: sS[row][80] (stride 81 to break conflicts)
    float* sS = smem;
    #pragma unroll
    for (int i = 0; i < 8; i++) {
        int row = tr * 8 + i;
        #pragma unroll
        for (int j = 0; j < 5; j++)
            sS[row * 81 + tc * 5 + j] = acc[i][j];
    }
    __syncthreads();

    // attn_score [h][n][1][t] -- per h, a block's 1280 floats are contiguous
    #pragma unroll
    for (int h = 0; h < N_HEADS; h++) {
        float* dst = outAttn + (size_t)h * N * N_TOK + (size_t)n0 * N_TOK;
        for (int i = tid; i < 128 * N_TOK; i += 256) {
            int row = i / N_TOK;
            int t = i - row * N_TOK;
            dst[i] = sS[row * 81 + h * N_TOK + t];
        }
    }

    // out[n][h*64+d] = sum_t sS[row][h*10+t] * keys[t][d]
    // thread handles d-chunk (tc*4 .. +3) for rows tr*8..tr*8+7, all heads;
    // keys chunk lives in registers, reused across all 64 (row,h) iterations.
    float4 kr[N_TOK];
    #pragma unroll
    for (int t = 0; t < N_TOK; t++)
        kr[t] = *(const float4*)(keys + t * N_HDIM + tc * 4);

    for (int i = 0; i < 8; i++) {
        int row = tr * 8 + i;
        #pragma unroll
        for (int h = 0; h < N_HEADS; h++) {
            float4 o = {0.f, 0.f, 0.f, 0.f};
            #pragma unroll
            for (int t = 0; t < N_TOK; t++) {
                float s = sS[row * 81 + h * N_TOK + t];
                o.x += s * kr[t].x;
                o.y += s * kr[t].y;
                o.z += s * kr[t].z;
                o.w += s * kr[t].w;
            }
            *(float4*)(outStyle + (size_t)(n0 + row) * N_EDIM + h * N_HDIM + tc * 4) = o;
        }
    }
}

extern "C" void kernel_launch(void* const* d_in, const int* in_sizes, int n_in,
                              void* d_out, int out_size, void* d_ws, size_t ws_size,
                              hipStream_t stream) {
    const float* inputs = (const float*)d_in[0];  // (N, 256)
    const float* embed  = (const float*)d_in[1];  // (10, 64)
    const float* Wq     = (const float*)d_in[2];  // (512, 256)
    const float* Wk     = (const float*)d_in[3];  // (512, 64)

    const int N = in_sizes[0] / N_QDIM;           // 131072

    float* Ws     = (float*)d_ws;                 // 256*80 floats
    float* keysWs = Ws + N_QDIM * NJ;             // 10*64 floats

    float* outStyle = (float*)d_out;                        // N*512
    float* outAttn  = outStyle + (size_t)N * N_EDIM;        // 8*N*10

    precompute_kernel<<<80, 256, 0, stream>>>(embed, Wq, Wk, Ws, keysWs);
    main_kernel<<<N / 128, 256, 0, stream>>>(inputs, Ws, keysWs, outStyle, outAttn, N);
}